// Round 6
// baseline (1034.800 us; speedup 1.0000x reference)
//
#include <hip/hip_runtime.h>
#include <stdint.h>
#include <math.h>

#define NN 50000          // nodes
#define NE 800000         // edges
#define NH 4              // heads

typedef __attribute__((ext_vector_type(8))) short short8;
typedef __attribute__((ext_vector_type(4))) float floatx4;

// ======================= bf16 helpers =======================
__device__ inline float bf2f(uint32_t u16)
{
    return __uint_as_float(u16 << 16);
}
__device__ inline uint16_t f2bf(float f)
{
    uint32_t u = __float_as_uint(f);
    uint32_t r = (u + 0x7fffu + ((u >> 16) & 1u)) >> 16;   // RNE
    return (uint16_t)r;
}
__device__ inline void unpk8(uint4 u, float* f)
{
    f[0] = bf2f(u.x & 0xffffu); f[1] = bf2f(u.x >> 16);
    f[2] = bf2f(u.y & 0xffffu); f[3] = bf2f(u.y >> 16);
    f[4] = bf2f(u.z & 0xffffu); f[5] = bf2f(u.z >> 16);
    f[6] = bf2f(u.w & 0xffffu); f[7] = bf2f(u.w >> 16);
}

// ======================= JAX threefry2x32 (partitionable mode) =======================
__host__ __device__ inline void tf2x32(uint32_t k0, uint32_t k1,
                                       uint32_t x0, uint32_t x1,
                                       uint32_t& o0, uint32_t& o1)
{
    uint32_t ks2 = k0 ^ k1 ^ 0x1BD11BDAu;
    x0 += k0; x1 += k1;
#define TF_R(r) { x0 += x1; x1 = (x1 << (r)) | (x1 >> (32 - (r))); x1 ^= x0; }
    TF_R(13) TF_R(15) TF_R(26) TF_R(6)
    x0 += k1;  x1 += ks2 + 1u;
    TF_R(17) TF_R(29) TF_R(16) TF_R(24)
    x0 += ks2; x1 += k0 + 2u;
    TF_R(13) TF_R(15) TF_R(26) TF_R(6)
    x0 += k0;  x1 += k1 + 3u;
    TF_R(17) TF_R(29) TF_R(16) TF_R(24)
    x0 += k1;  x1 += ks2 + 4u;
    TF_R(13) TF_R(15) TF_R(26) TF_R(6)
    x0 += ks2; x1 += k0 + 5u;
#undef TF_R
    o0 = x0; o1 = x1;
}

__device__ inline uint32_t jax_bits32(uint32_t k0, uint32_t k1, uint32_t idx)
{
    uint32_t a, b;
    tf2x32(k0, k1, 0u, idx, a, b);
    return a ^ b;
}

__device__ inline float jax_u01(uint32_t bits)
{
    return __uint_as_float((bits >> 9) | 0x3f800000u) - 1.0f;
}

// XLA ErfInv32 (Giles 2012)
__device__ inline float erfinv_f(float x)
{
    float w = -log1pf(-x * x);
    float p;
    if (w < 5.0f) {
        w = w - 2.5f;
        p = 2.81022636e-08f;
        p = fmaf(p, w, 3.43273939e-07f);
        p = fmaf(p, w, -3.5233877e-06f);
        p = fmaf(p, w, -4.39150654e-06f);
        p = fmaf(p, w, 0.00021858087f);
        p = fmaf(p, w, -0.00125372503f);
        p = fmaf(p, w, -0.00417768164f);
        p = fmaf(p, w, 0.246640727f);
        p = fmaf(p, w, 1.50140941f);
    } else {
        w = sqrtf(w) - 3.0f;
        p = -0.000200214257f;
        p = fmaf(p, w, 0.000100950558f);
        p = fmaf(p, w, 0.00134934322f);
        p = fmaf(p, w, -0.00367342844f);
        p = fmaf(p, w, 0.00573950773f);
        p = fmaf(p, w, -0.0076224613f);
        p = fmaf(p, w, 0.00943887047f);
        p = fmaf(p, w, 1.00167406f);
        p = fmaf(p, w, 2.83297682f);
    }
    return p * x;
}

// ======================= utility kernels =======================
__global__ __launch_bounds__(256) void fill_u32_k(uint32_t* p, uint32_t v, int n)
{
    int i = blockIdx.x * blockDim.x + threadIdx.x;
    if (i < n) p[i] = v;
}

__global__ __launch_bounds__(256) void f2bf_vec_k(const float* __restrict__ in,
                                                  uint16_t* __restrict__ out, int n)
{
    int i = (blockIdx.x * blockDim.x + threadIdx.x) * 4;
    if (i >= n) return;
    float4 v = *(const float4*)(in + i);
    out[i + 0] = f2bf(v.x); out[i + 1] = f2bf(v.y);
    out[i + 2] = f2bf(v.z); out[i + 3] = f2bf(v.w);
}

// ======================= weight convert: fp32 [B][K][C] -> bf16 Wt [B*C][K] =======================
struct WSeg { const float* src; int B, K, C, off; };
struct WSegs { WSeg s[18]; };

__global__ __launch_bounds__(256) void wconv_k(WSegs segs, uint16_t* __restrict__ Wt)
{
    WSeg sg = segs.s[blockIdx.y];
    int n = sg.B * sg.K * sg.C;
    int i = blockIdx.x * 256 + threadIdx.x;
    if (i >= n) return;
    int kc = sg.K * sg.C;
    int b = i / kc;
    int rr = i - b * kc;
    int k = rr / sg.C;
    int c = rr - k * sg.C;
    Wt[(size_t)sg.off + (size_t)(b * sg.C + c) * sg.K + k] = f2bf(sg.src[i]);
}

// ======================= CSR build (once per launch) =======================
__global__ __launch_bounds__(256) void hist_k(const int* __restrict__ dst, int* __restrict__ deg)
{
    int e = blockIdx.x * blockDim.x + threadIdx.x;
    if (e < NE) atomicAdd(&deg[dst[e]], 1);
}

#define SCAN_CHUNK 1024
#define SCAN_NBLK  ((NN + SCAN_CHUNK - 1) / SCAN_CHUNK)   // 49

__global__ __launch_bounds__(256) void scan1_k(const int* __restrict__ deg,
                                               int* __restrict__ rowptr,
                                               int* __restrict__ bsums)
{
    __shared__ int lds[256];
    int b = blockIdx.x, t = threadIdx.x;
    int base = b * SCAN_CHUNK + t * 4;
    int v0 = (base + 0 < NN) ? deg[base + 0] : 0;
    int v1 = (base + 1 < NN) ? deg[base + 1] : 0;
    int v2 = (base + 2 < NN) ? deg[base + 2] : 0;
    int v3 = (base + 3 < NN) ? deg[base + 3] : 0;
    int s = v0 + v1 + v2 + v3;
    lds[t] = s;
    __syncthreads();
    for (int off = 1; off < 256; off <<= 1) {
        int x = (t >= off) ? lds[t - off] : 0;
        __syncthreads();
        lds[t] += x;
        __syncthreads();
    }
    int excl = lds[t] - s;
    if (base + 0 < NN) rowptr[base + 0] = excl;
    if (base + 1 < NN) rowptr[base + 1] = excl + v0;
    if (base + 2 < NN) rowptr[base + 2] = excl + v0 + v1;
    if (base + 3 < NN) rowptr[base + 3] = excl + v0 + v1 + v2;
    if (t == 255) bsums[b] = lds[255];
}

__global__ void scan2_k(int* bsums)
{
    if (threadIdx.x == 0 && blockIdx.x == 0) {
        int run = 0;
        for (int i = 0; i < SCAN_NBLK; i++) { int t = bsums[i]; bsums[i] = run; run += t; }
    }
}

__global__ __launch_bounds__(256) void scan3_k(int* __restrict__ rowptr,
                                               const int* __restrict__ bsums,
                                               int* __restrict__ cursor)
{
    int i = blockIdx.x * blockDim.x + threadIdx.x;
    if (i < NN) {
        int r = rowptr[i] + bsums[i / SCAN_CHUNK];
        rowptr[i] = r;
        cursor[i] = r;
    }
    if (i == 0) rowptr[NN] = NE;
}

__global__ __launch_bounds__(256) void csr_scatter_k(const int* __restrict__ src,
                                                     const int* __restrict__ dst,
                                                     int* __restrict__ cursor,
                                                     int* __restrict__ esrc)
{
    int e = blockIdx.x * blockDim.x + threadIdx.x;
    if (e >= NE) return;
    int d = dst[e];
    int pos = atomicAdd(&cursor[d], 1);
    esrc[pos] = src[e];
}

// ======================= bf16 MFMA GEMM =======================
template<int K, int CH>
__global__ __launch_bounds__(256) void gemm_mfma_k(const uint16_t* __restrict__ A,
                                                   const uint16_t* __restrict__ Wt,
                                                   uint16_t* __restrict__ C,
                                                   int Ntot, int relu)
{
    constexpr int KP = K + 8;
    constexpr int KC = K / 8;
    constexpr int NT = CH / 16;
    extern __shared__ uint16_t smem[];
    uint16_t* As = smem;             // 64 x KP
    uint16_t* Ws = smem + 64 * KP;   // CH x KP

    const int tid = threadIdx.x;
    const int row0 = blockIdx.x * 64;
    const int w  = tid >> 6;
    const int l  = tid & 63;
    const int lm = l & 15;
    const int lq = l >> 4;

    for (int i = tid; i < 64 * KC; i += 256) {
        int r = i / KC, c = i - r * KC;
        int gr = row0 + r; if (gr >= NN) gr = NN - 1;
        uint4 vv = *(const uint4*)(A + (size_t)gr * K + c * 8);
        *(uint4*)(As + r * KP + c * 8) = vv;
    }

    const uint16_t* a_base = As + (16 * w + lm) * KP + lq * 8;
    const uint16_t* b_base = Ws + lm * KP + lq * 8;

    const int nchunks = Ntot / CH;
    for (int ch = 0; ch < nchunks; ch++) {
        __syncthreads();
        for (int i = tid; i < CH * KC; i += 256) {
            int r = i / KC, c = i - r * KC;
            uint4 vv = *(const uint4*)(Wt + (size_t)(ch * CH + r) * K + c * 8);
            *(uint4*)(Ws + r * KP + c * 8) = vv;
        }
        __syncthreads();

        floatx4 acc[NT];
#pragma unroll
        for (int nt = 0; nt < NT; nt++) acc[nt] = (floatx4){0.f, 0.f, 0.f, 0.f};

#pragma unroll
        for (int ks = 0; ks < K / 32; ks++) {
            short8 av = *(const short8*)(a_base + ks * 32);
#pragma unroll
            for (int nt = 0; nt < NT; nt++) {
                short8 bv = *(const short8*)(b_base + nt * 16 * KP + ks * 32);
                acc[nt] = __builtin_amdgcn_mfma_f32_16x16x32_bf16(av, bv, acc[nt], 0, 0, 0);
            }
        }

        const int rbase = row0 + 16 * w + lq * 4;
        const int cbase = ch * CH + lm;
#pragma unroll
        for (int nt = 0; nt < NT; nt++) {
#pragma unroll
            for (int r = 0; r < 4; r++) {
                int gr = rbase + r;
                if (gr < NN) {
                    float v = acc[nt][r];
                    if (relu) v = fmaxf(v, 0.0f);
                    C[(size_t)gr * Ntot + cbase + nt * 16] = f2bf(v);
                }
            }
        }
    }
}

// ======================= attention: 4 nodes/block, 1 wave each =======================
// qkv layout: [N][3*OD] bf16 rows: [q | k | v]. Wave wv handles node blockIdx.x*4+wv.
// Uniform chunk trip-count across the block -> __syncthreads is non-divergent.
// Phase 1: lanes = (16 edge-slots x 4 heads), scores -> sc[j][h] (bank 4e+h, <=2-way).
// Phase 2: lanes = (4 edge-subslots x 16 dim-lanes), 16B/lane v loads, shfl-reduce groups.
template<int DH>
__global__ __launch_bounds__(256) void attn_wave_k(const uint16_t* __restrict__ qkv,
                                                   const int* __restrict__ rowptr,
                                                   const int* __restrict__ esrc,
                                                   uint16_t* __restrict__ agg,
                                                   float scale)
{
    constexpr int OD  = NH * DH;     // 128 / 64
    constexpr int STR = 3 * OD;
    constexpr int QU  = DH / 8;      // uint4 loads per head slice (4 / 2)
    constexpr int CAP = 64;          // edges per chunk
    constexpr int NP  = CAP / 16;    // phase-1 passes (4)
    constexpr int FV  = OD / 16;     // dims per lane in phase 2 (8 / 4)

    __shared__ float s_sc[4][CAP][4];
    __shared__ int   s_sn[4][CAP];
    __shared__ float s_hdr[4][8];    // [0..3]=corr, [4..7]=l
    __shared__ int   s_mx[4];

    const int wv   = threadIdx.x >> 6;
    const int lane = threadIdx.x & 63;
    const int n    = blockIdx.x * 4 + wv;      // NN%4==0 -> always < NN
    const int h1   = lane & 3;
    const int e    = lane >> 2;
    const int g    = lane >> 4;                // phase-2 edge subslot
    const int dl   = lane & 15;                // phase-2 dim-lane
    const int h2   = dl >> 2;                  // head of this lane's dim slots

    // q fragment for phase-1 head
    float qf[DH];
    {
        const uint4* qp = (const uint4*)(qkv + (size_t)n * STR + h1 * DH);
#pragma unroll
        for (int i = 0; i < QU; i++) { uint4 u = qp[i]; unpk8(u, &qf[i * 8]); }
    }

    const int j0 = rowptr[n], j1 = rowptr[n + 1];
    if (lane == 0) s_mx[wv] = (j1 - j0 + CAP - 1) / CAP;
    __syncthreads();
    const int cmax = max(max(s_mx[0], s_mx[1]), max(s_mx[2], s_mx[3]));

    float m = -INFINITY, l = 0.0f;
    float acc[FV];
#pragma unroll
    for (int i = 0; i < FV; i++) acc[i] = 0.0f;

    const int voff = 2 * OD + dl * FV;

    for (int ch = 0; ch < cmax; ch++) {
        const int c0 = j0 + ch * CAP;
        const int cn = min(max(j1 - c0, 0), CAP);

        if (lane < cn) s_sn[wv][lane] = esrc[c0 + lane];
        __syncthreads();

        // ---- phase 1: scores ----
        float sc[NP];
        float lm = -INFINITY;
#pragma unroll
        for (int t = 0; t < NP; t++) {
            const int j = e + 16 * t;
            float s = -INFINITY;
            if (j < cn) {
                const int sn = s_sn[wv][j];
                const uint4* kp = (const uint4*)(qkv + (size_t)sn * STR + OD + h1 * DH);
                s = 0.0f;
#pragma unroll
                for (int i = 0; i < QU; i++) {
                    uint4 u = kp[i];
                    float kf[8];
                    unpk8(u, kf);
                    s = fmaf(qf[i * 8 + 0], kf[0], s); s = fmaf(qf[i * 8 + 1], kf[1], s);
                    s = fmaf(qf[i * 8 + 2], kf[2], s); s = fmaf(qf[i * 8 + 3], kf[3], s);
                    s = fmaf(qf[i * 8 + 4], kf[4], s); s = fmaf(qf[i * 8 + 5], kf[5], s);
                    s = fmaf(qf[i * 8 + 6], kf[6], s); s = fmaf(qf[i * 8 + 7], kf[7], s);
                }
                s *= scale;
            }
            sc[t] = s;
            lm = fmaxf(lm, s);
        }
#pragma unroll
        for (int msk = 4; msk <= 32; msk <<= 1) lm = fmaxf(lm, __shfl_xor(lm, msk, 64));
        const float mn = fmaxf(m, lm);
        const float corr = (m == mn) ? 1.0f : expf(m - mn);
        m = mn;

        float ls = 0.0f;
#pragma unroll
        for (int t = 0; t < NP; t++) {
            const int j = e + 16 * t;
            if (j < cn) {
                float p = expf(sc[t] - mn);
                s_sc[wv][j][h1] = p;
                ls += p;
            }
        }
#pragma unroll
        for (int msk = 4; msk <= 32; msk <<= 1) ls += __shfl_xor(ls, msk, 64);
        l = l * corr + ls;
        if (e == 0) s_hdr[wv][h1] = corr;
        __syncthreads();

        // ---- phase 2: 4 edges x 16 dim-lanes per pass ----
        const float c2 = s_hdr[wv][h2];
#pragma unroll
        for (int i = 0; i < FV; i++) acc[i] *= c2;

        for (int jb = 0; jb < cn; jb += 4) {
            const int j = jb + g;
            if (j < cn) {
                const float alpha = s_sc[wv][j][h2];
                const int sn = s_sn[wv][j];
                if constexpr (FV == 8) {
                    uint4 u = *(const uint4*)(qkv + (size_t)sn * STR + voff);
                    float vf[8];
                    unpk8(u, vf);
#pragma unroll
                    for (int i = 0; i < 8; i++) acc[i] = fmaf(alpha, vf[i], acc[i]);
                } else {
                    uint2 u = *(const uint2*)(qkv + (size_t)sn * STR + voff);
                    acc[0] = fmaf(alpha, bf2f(u.x & 0xffffu), acc[0]);
                    acc[1] = fmaf(alpha, bf2f(u.x >> 16),     acc[1]);
                    acc[2] = fmaf(alpha, bf2f(u.y & 0xffffu), acc[2]);
                    acc[3] = fmaf(alpha, bf2f(u.y >> 16),     acc[3]);
                }
            }
        }
        __syncthreads();
    }

    // publish l, reduce groups, normalize, write
    if (e == 0) s_hdr[wv][4 + h1] = l;
    __syncthreads();
    const float lf = s_hdr[wv][4 + h2];
    const float inv = (lf > 0.0f) ? 1.0f / lf : 0.0f;
#pragma unroll
    for (int i = 0; i < FV; i++) {
        acc[i] += __shfl_xor(acc[i], 16, 64);
        acc[i] += __shfl_xor(acc[i], 32, 64);
    }
    if (g == 0) {
        uint16_t* op = agg + (size_t)n * OD + dl * FV;
        uint32_t wword[FV / 2];
#pragma unroll
        for (int i = 0; i < FV / 2; i++)
            wword[i] = (uint32_t)f2bf(acc[2 * i] * inv) | ((uint32_t)f2bf(acc[2 * i + 1] * inv) << 16);
        if constexpr (FV == 8) {
            *(uint4*)op = make_uint4(wword[0], wword[1], wword[2], wword[3]);
        } else {
            *(uint2*)op = make_uint2(wword[0], wword[1]);
        }
    }
}

// ======================= norms / dropout / reparam =======================
__global__ __launch_bounds__(256) void norm_relu_drop_k(const uint16_t* __restrict__ in,
                                                        uint16_t* __restrict__ out,
                                                        uint32_t k0, uint32_t k1)
{
    int row = blockIdx.x * 4 + (threadIdx.x >> 6);
    int lane = threadIdx.x & 63;
    if (row >= NN) return;
    const uint16_t* r = in + (size_t)row * 128;
    float a = bf2f(r[lane]), b = bf2f(r[lane + 64]);
    float ss = fmaf(a, a, b * b);
#pragma unroll
    for (int m = 32; m > 0; m >>= 1) ss += __shfl_xor(ss, m, 64);
    float d = fmaxf(sqrtf(ss), 1e-12f);
    float ya = fmaxf(a / d, 0.0f);
    float yb = fmaxf(b / d, 0.0f);
    uint32_t ia = (uint32_t)row * 128u + (uint32_t)lane;
    float ua = jax_u01(jax_bits32(k0, k1, ia));
    float ub = jax_u01(jax_bits32(k0, k1, ia + 64u));
    uint16_t* o = out + (size_t)row * 128;
    o[lane]      = f2bf((ua < 0.5f) ? ya * 2.0f : 0.0f);
    o[lane + 64] = f2bf((ub < 0.5f) ? yb * 2.0f : 0.0f);
}

__global__ __launch_bounds__(256) void norm64_k(const uint16_t* __restrict__ in,
                                                float* __restrict__ out)
{
    int row = blockIdx.x * 4 + (threadIdx.x >> 6);
    int lane = threadIdx.x & 63;
    if (row >= NN) return;
    float a = bf2f(in[(size_t)row * 64 + lane]);
    float ss = a * a;
#pragma unroll
    for (int m = 32; m > 0; m >>= 1) ss += __shfl_xor(ss, m, 64);
    float d = fmaxf(sqrtf(ss), 1e-12f);
    out[(size_t)row * 64 + lane] = a / d;
}

__global__ __launch_bounds__(256) void final_z_k(const float* __restrict__ mu,
                                                 const float* __restrict__ lv,
                                                 float* __restrict__ out,
                                                 uint32_t k0, uint32_t k1)
{
    int i = blockIdx.x * blockDim.x + threadIdx.x;
    if (i >= NN * 64) return;
    const float LO = -0.99999994f; // nextafter(-1, 0) in f32
    float u01 = jax_u01(jax_bits32(k0, k1, (uint32_t)i));
    float u = fmaxf(LO, fmaf(u01, 2.0f, LO));
    float eps = 1.41421354f * erfinv_f(u);
    float stdv = expf(lv[i]) + 1e-12f;
    out[i] = fmaf(eps, stdv, mu[i]);
}

// ======================= host side =======================
struct Bufs {
    uint16_t* Wt;
    uint16_t* feat_bf;
    uint16_t* qkv;
    uint16_t* agg;
    uint16_t* h1;
    uint16_t* h2;
    uint16_t* x;
    float* mu;
    float* lv;
    int* rowptr;
    int* cursor;
    int* bsums;
    int* esrc;
};

static void gemm_launch(int K, const uint16_t* A, const uint16_t* Wt, uint16_t* C,
                        int Ntot, int relu, hipStream_t s)
{
    int grid = (NN + 63) / 64;
    switch (K) {
    case 256: {
        size_t lds = (size_t)(64 + 32) * (256 + 8) * 2;
        gemm_mfma_k<256, 32><<<grid, 256, lds, s>>>(A, Wt, C, Ntot, relu);
        break;
    }
    case 128: {
        size_t lds = (size_t)(64 + 64) * (128 + 8) * 2;
        gemm_mfma_k<128, 64><<<grid, 256, lds, s>>>(A, Wt, C, Ntot, relu);
        break;
    }
    default: {
        size_t lds = (size_t)(64 + 64) * (64 + 8) * 2;
        gemm_mfma_k<64, 64><<<grid, 256, lds, s>>>(A, Wt, C, Ntot, relu);
        break;
    }
    }
}

static void run_gt_layer(const uint16_t* h_in, int K, int od,
                         const uint16_t* wqkv_t, const uint16_t* wo_t, bool relu,
                         uint16_t* h_out, const Bufs& B, hipStream_t stream)
{
    const int dh = od / NH;
    const float scale = 1.0f / sqrtf((float)dh);

    gemm_launch(K, h_in, wqkv_t, B.qkv, 3 * od, 0, stream);

    if (dh == 32)
        attn_wave_k<32><<<NN / 4, 256, 0, stream>>>(B.qkv, B.rowptr, B.esrc, B.agg, scale);
    else
        attn_wave_k<16><<<NN / 4, 256, 0, stream>>>(B.qkv, B.rowptr, B.esrc, B.agg, scale);

    gemm_launch(od, B.agg, wo_t, h_out, od, relu ? 1 : 0, stream);
}

extern "C" void kernel_launch(void* const* d_in, const int* in_sizes, int n_in,
                              void* d_out, int out_size, void* d_ws, size_t ws_size,
                              hipStream_t stream)
{
    const float* feat    = (const float*)d_in[0];
    const int*   src     = (const int*)d_in[1];
    const int*   dst     = (const int*)d_in[2];
    const float* wqkv1_0 = (const float*)d_in[3];
    const float* wqkv1_r = (const float*)d_in[4];
    const float* wo1     = (const float*)d_in[5];
    const float* wqkv2_0 = (const float*)d_in[6];
    const float* wqkv2_r = (const float*)d_in[7];
    const float* wo2     = (const float*)d_in[8];
    const float* wqkv3_0 = (const float*)d_in[9];
    const float* wqkv3_r = (const float*)d_in[10];
    const float* wo3     = (const float*)d_in[11];
    float* out = (float*)d_out;

    char* wp = (char*)d_ws;
    auto alloc = [&](size_t bytes) { char* p = wp; wp += (bytes + 255) & ~(size_t)255; return p; };

    WSegs segs;
    int offs[18];
    int acc_off = 0;
    auto seg = [&](int i, const float* p, int Bc, int Kc, int Cc) {
        segs.s[i].src = p; segs.s[i].B = Bc; segs.s[i].K = Kc; segs.s[i].C = Cc;
        segs.s[i].off = acc_off; offs[i] = acc_off; acc_off += Bc * Kc * Cc;
    };
    seg(0,  wqkv1_0,                 3, 256, 128);
    seg(1,  wqkv1_r,                 3, 128, 128);
    seg(2,  wqkv1_r + 3 * 128 * 128, 3, 128, 128);
    seg(3,  wo1,                     1, 128, 128);
    seg(4,  wo1 + 128 * 128,         1, 128, 128);
    seg(5,  wo1 + 2 * 128 * 128,     1, 128, 128);
    seg(6,  wqkv2_0,                 3, 128, 64);
    seg(7,  wqkv2_r,                 3, 64, 64);
    seg(8,  wqkv2_r + 3 * 64 * 64,   3, 64, 64);
    seg(9,  wo2,                     1, 64, 64);
    seg(10, wo2 + 64 * 64,           1, 64, 64);
    seg(11, wo2 + 2 * 64 * 64,       1, 64, 64);
    seg(12, wqkv3_0,                 3, 128, 64);
    seg(13, wqkv3_r,                 3, 64, 64);
    seg(14, wqkv3_r + 3 * 64 * 64,   3, 64, 64);
    seg(15, wo3,                     1, 64, 64);
    seg(16, wo3 + 64 * 64,           1, 64, 64);
    seg(17, wo3 + 2 * 64 * 64,       1, 64, 64);

    Bufs B;
    B.Wt      = (uint16_t*)alloc((size_t)acc_off * 2);
    B.feat_bf = (uint16_t*)alloc((size_t)NN * 256 * 2);
    B.qkv     = (uint16_t*)alloc((size_t)NN * 384 * 2);
    B.agg     = (uint16_t*)alloc((size_t)NN * 128 * 2);
    B.h1      = (uint16_t*)alloc((size_t)NN * 128 * 2);
    B.h2      = (uint16_t*)alloc((size_t)NN * 128 * 2);
    B.x       = (uint16_t*)alloc((size_t)NN * 128 * 2);
    B.mu      = (float*)alloc((size_t)NN * 64 * 4);
    B.lv      = (float*)alloc((size_t)NN * 64 * 4);
    B.rowptr  = (int*)alloc((size_t)(NN + 1) * 4);
    B.cursor  = (int*)alloc((size_t)NN * 4);
    B.bsums   = (int*)alloc((size_t)SCAN_NBLK * 4);
    B.esrc    = (int*)alloc((size_t)NE * 4);

    wconv_k<<<dim3(384, 18), 256, 0, stream>>>(segs, B.Wt);
    f2bf_vec_k<<<(NN * 256 / 4 + 255) / 256, 256, 0, stream>>>(feat, B.feat_bf, NN * 256);

    fill_u32_k<<<(NN + 255) / 256, 256, 0, stream>>>((uint32_t*)B.cursor, 0u, NN);
    hist_k<<<(NE + 255) / 256, 256, 0, stream>>>(dst, B.cursor);
    scan1_k<<<SCAN_NBLK, 256, 0, stream>>>(B.cursor, B.rowptr, B.bsums);
    scan2_k<<<1, 64, 0, stream>>>(B.bsums);
    scan3_k<<<(NN + 255) / 256, 256, 0, stream>>>(B.rowptr, B.bsums, B.cursor);
    csr_scatter_k<<<(NE + 255) / 256, 256, 0, stream>>>(src, dst, B.cursor, B.esrc);

    uint32_t kd0, kd1, ke0, ke1;
    tf2x32(0u, 42u, 0u, 0u, kd0, kd1);
    tf2x32(0u, 42u, 0u, 1u, ke0, ke1);

    run_gt_layer(B.feat_bf, 256, 128, B.Wt + offs[0], B.Wt + offs[3], true,  B.h1, B, stream);
    run_gt_layer(B.h1,      128, 128, B.Wt + offs[1], B.Wt + offs[4], true,  B.h2, B, stream);
    run_gt_layer(B.h2,      128, 128, B.Wt + offs[2], B.Wt + offs[5], false, B.h1, B, stream);

    norm_relu_drop_k<<<NN / 4, 256, 0, stream>>>(B.h1, B.x, kd0, kd1);

    run_gt_layer(B.x,  128, 64, B.Wt + offs[6], B.Wt + offs[9],  true,  B.h1, B, stream);
    run_gt_layer(B.h1, 64,  64, B.Wt + offs[7], B.Wt + offs[10], true,  B.h2, B, stream);
    run_gt_layer(B.h2, 64,  64, B.Wt + offs[8], B.Wt + offs[11], false, B.h1, B, stream);
    norm64_k<<<NN / 4, 256, 0, stream>>>(B.h1, B.mu);

    run_gt_layer(B.x,  128, 64, B.Wt + offs[12], B.Wt + offs[15], true,  B.h1, B, stream);
    run_gt_layer(B.h1, 64,  64, B.Wt + offs[13], B.Wt + offs[16], true,  B.h2, B, stream);
    run_gt_layer(B.h2, 64,  64, B.Wt + offs[14], B.Wt + offs[17], false, B.h1, B, stream);
    norm64_k<<<NN / 4, 256, 0, stream>>>(B.h1, B.lv);

    final_z_k<<<(NN * 64 + 255) / 256, 256, 0, stream>>>(B.mu, B.lv, out, ke0, ke1);
}

// Round 7
// 981.000 us; speedup vs baseline: 1.0548x; 1.0548x over previous
//
#include <hip/hip_runtime.h>
#include <stdint.h>
#include <math.h>

#define NN 50000          // nodes
#define NE 800000         // edges
#define NH 4              // heads

typedef __attribute__((ext_vector_type(8))) short short8;
typedef __attribute__((ext_vector_type(4))) float floatx4;

// ======================= bf16 helpers =======================
__device__ inline float bf2f(uint32_t u16)
{
    return __uint_as_float(u16 << 16);
}
__device__ inline uint16_t f2bf(float f)
{
    uint32_t u = __float_as_uint(f);
    uint32_t r = (u + 0x7fffu + ((u >> 16) & 1u)) >> 16;   // RNE
    return (uint16_t)r;
}
__device__ inline void unpk8(uint4 u, float* f)
{
    f[0] = bf2f(u.x & 0xffffu); f[1] = bf2f(u.x >> 16);
    f[2] = bf2f(u.y & 0xffffu); f[3] = bf2f(u.y >> 16);
    f[4] = bf2f(u.z & 0xffffu); f[5] = bf2f(u.z >> 16);
    f[6] = bf2f(u.w & 0xffffu); f[7] = bf2f(u.w >> 16);
}

// ======================= JAX threefry2x32 (partitionable mode) =======================
__host__ __device__ inline void tf2x32(uint32_t k0, uint32_t k1,
                                       uint32_t x0, uint32_t x1,
                                       uint32_t& o0, uint32_t& o1)
{
    uint32_t ks2 = k0 ^ k1 ^ 0x1BD11BDAu;
    x0 += k0; x1 += k1;
#define TF_R(r) { x0 += x1; x1 = (x1 << (r)) | (x1 >> (32 - (r))); x1 ^= x0; }
    TF_R(13) TF_R(15) TF_R(26) TF_R(6)
    x0 += k1;  x1 += ks2 + 1u;
    TF_R(17) TF_R(29) TF_R(16) TF_R(24)
    x0 += ks2; x1 += k0 + 2u;
    TF_R(13) TF_R(15) TF_R(26) TF_R(6)
    x0 += k0;  x1 += k1 + 3u;
    TF_R(17) TF_R(29) TF_R(16) TF_R(24)
    x0 += k1;  x1 += ks2 + 4u;
    TF_R(13) TF_R(15) TF_R(26) TF_R(6)
    x0 += ks2; x1 += k0 + 5u;
#undef TF_R
    o0 = x0; o1 = x1;
}

__device__ inline uint32_t jax_bits32(uint32_t k0, uint32_t k1, uint32_t idx)
{
    uint32_t a, b;
    tf2x32(k0, k1, 0u, idx, a, b);
    return a ^ b;
}

__device__ inline float jax_u01(uint32_t bits)
{
    return __uint_as_float((bits >> 9) | 0x3f800000u) - 1.0f;
}

// XLA ErfInv32 (Giles 2012)
__device__ inline float erfinv_f(float x)
{
    float w = -log1pf(-x * x);
    float p;
    if (w < 5.0f) {
        w = w - 2.5f;
        p = 2.81022636e-08f;
        p = fmaf(p, w, 3.43273939e-07f);
        p = fmaf(p, w, -3.5233877e-06f);
        p = fmaf(p, w, -4.39150654e-06f);
        p = fmaf(p, w, 0.00021858087f);
        p = fmaf(p, w, -0.00125372503f);
        p = fmaf(p, w, -0.00417768164f);
        p = fmaf(p, w, 0.246640727f);
        p = fmaf(p, w, 1.50140941f);
    } else {
        w = sqrtf(w) - 3.0f;
        p = -0.000200214257f;
        p = fmaf(p, w, 0.000100950558f);
        p = fmaf(p, w, 0.00134934322f);
        p = fmaf(p, w, -0.00367342844f);
        p = fmaf(p, w, 0.00573950773f);
        p = fmaf(p, w, -0.0076224613f);
        p = fmaf(p, w, 0.00943887047f);
        p = fmaf(p, w, 1.00167406f);
        p = fmaf(p, w, 2.83297682f);
    }
    return p * x;
}

// ======================= utility kernels =======================
__global__ __launch_bounds__(256) void fill_u32_k(uint32_t* p, uint32_t v, int n)
{
    int i = blockIdx.x * blockDim.x + threadIdx.x;
    if (i < n) p[i] = v;
}

__global__ __launch_bounds__(256) void f2bf_vec_k(const float* __restrict__ in,
                                                  uint16_t* __restrict__ out, int n)
{
    int i = (blockIdx.x * blockDim.x + threadIdx.x) * 4;
    if (i >= n) return;
    float4 v = *(const float4*)(in + i);
    out[i + 0] = f2bf(v.x); out[i + 1] = f2bf(v.y);
    out[i + 2] = f2bf(v.z); out[i + 3] = f2bf(v.w);
}

// ======================= weight convert: fp32 [B][K][C] -> bf16 Wt [B*C][K] =======================
struct WSeg { const float* src; int B, K, C, off; };
struct WSegs { WSeg s[18]; };

__global__ __launch_bounds__(256) void wconv_k(WSegs segs, uint16_t* __restrict__ Wt)
{
    WSeg sg = segs.s[blockIdx.y];
    int n = sg.B * sg.K * sg.C;
    int i = blockIdx.x * 256 + threadIdx.x;
    if (i >= n) return;
    int kc = sg.K * sg.C;
    int b = i / kc;
    int rr = i - b * kc;
    int k = rr / sg.C;
    int c = rr - k * sg.C;
    Wt[(size_t)sg.off + (size_t)(b * sg.C + c) * sg.K + k] = f2bf(sg.src[i]);
}

// ======================= CSR build (once per launch) =======================
__global__ __launch_bounds__(256) void hist_k(const int* __restrict__ dst, int* __restrict__ deg)
{
    int e = blockIdx.x * blockDim.x + threadIdx.x;
    if (e < NE) atomicAdd(&deg[dst[e]], 1);
}

#define SCAN_CHUNK 1024
#define SCAN_NBLK  ((NN + SCAN_CHUNK - 1) / SCAN_CHUNK)   // 49

__global__ __launch_bounds__(256) void scan1_k(const int* __restrict__ deg,
                                               int* __restrict__ rowptr,
                                               int* __restrict__ bsums)
{
    __shared__ int lds[256];
    int b = blockIdx.x, t = threadIdx.x;
    int base = b * SCAN_CHUNK + t * 4;
    int v0 = (base + 0 < NN) ? deg[base + 0] : 0;
    int v1 = (base + 1 < NN) ? deg[base + 1] : 0;
    int v2 = (base + 2 < NN) ? deg[base + 2] : 0;
    int v3 = (base + 3 < NN) ? deg[base + 3] : 0;
    int s = v0 + v1 + v2 + v3;
    lds[t] = s;
    __syncthreads();
    for (int off = 1; off < 256; off <<= 1) {
        int x = (t >= off) ? lds[t - off] : 0;
        __syncthreads();
        lds[t] += x;
        __syncthreads();
    }
    int excl = lds[t] - s;
    if (base + 0 < NN) rowptr[base + 0] = excl;
    if (base + 1 < NN) rowptr[base + 1] = excl + v0;
    if (base + 2 < NN) rowptr[base + 2] = excl + v0 + v1;
    if (base + 3 < NN) rowptr[base + 3] = excl + v0 + v1 + v2;
    if (t == 255) bsums[b] = lds[255];
}

__global__ void scan2_k(int* bsums)
{
    if (threadIdx.x == 0 && blockIdx.x == 0) {
        int run = 0;
        for (int i = 0; i < SCAN_NBLK; i++) { int t = bsums[i]; bsums[i] = run; run += t; }
    }
}

__global__ __launch_bounds__(256) void scan3_k(int* __restrict__ rowptr,
                                               const int* __restrict__ bsums,
                                               int* __restrict__ cursor)
{
    int i = blockIdx.x * blockDim.x + threadIdx.x;
    if (i < NN) {
        int r = rowptr[i] + bsums[i / SCAN_CHUNK];
        rowptr[i] = r;
        cursor[i] = r;
    }
    if (i == 0) rowptr[NN] = NE;
}

__global__ __launch_bounds__(256) void csr_scatter_k(const int* __restrict__ src,
                                                     const int* __restrict__ dst,
                                                     int* __restrict__ cursor,
                                                     int* __restrict__ esrc)
{
    int e = blockIdx.x * blockDim.x + threadIdx.x;
    if (e >= NE) return;
    int d = dst[e];
    int pos = atomicAdd(&cursor[d], 1);
    esrc[pos] = src[e];
}

// ======================= bf16 MFMA GEMM =======================
template<int K, int CH>
__global__ __launch_bounds__(256) void gemm_mfma_k(const uint16_t* __restrict__ A,
                                                   const uint16_t* __restrict__ Wt,
                                                   uint16_t* __restrict__ C,
                                                   int Ntot, int relu)
{
    constexpr int KP = K + 8;
    constexpr int KC = K / 8;
    constexpr int NT = CH / 16;
    extern __shared__ uint16_t smem[];
    uint16_t* As = smem;             // 64 x KP
    uint16_t* Ws = smem + 64 * KP;   // CH x KP

    const int tid = threadIdx.x;
    const int row0 = blockIdx.x * 64;
    const int w  = tid >> 6;
    const int l  = tid & 63;
    const int lm = l & 15;
    const int lq = l >> 4;

    for (int i = tid; i < 64 * KC; i += 256) {
        int r = i / KC, c = i - r * KC;
        int gr = row0 + r; if (gr >= NN) gr = NN - 1;
        uint4 vv = *(const uint4*)(A + (size_t)gr * K + c * 8);
        *(uint4*)(As + r * KP + c * 8) = vv;
    }

    const uint16_t* a_base = As + (16 * w + lm) * KP + lq * 8;
    const uint16_t* b_base = Ws + lm * KP + lq * 8;

    const int nchunks = Ntot / CH;
    for (int ch = 0; ch < nchunks; ch++) {
        __syncthreads();
        for (int i = tid; i < CH * KC; i += 256) {
            int r = i / KC, c = i - r * KC;
            uint4 vv = *(const uint4*)(Wt + (size_t)(ch * CH + r) * K + c * 8);
            *(uint4*)(Ws + r * KP + c * 8) = vv;
        }
        __syncthreads();

        floatx4 acc[NT];
#pragma unroll
        for (int nt = 0; nt < NT; nt++) acc[nt] = (floatx4){0.f, 0.f, 0.f, 0.f};

#pragma unroll
        for (int ks = 0; ks < K / 32; ks++) {
            short8 av = *(const short8*)(a_base + ks * 32);
#pragma unroll
            for (int nt = 0; nt < NT; nt++) {
                short8 bv = *(const short8*)(b_base + nt * 16 * KP + ks * 32);
                acc[nt] = __builtin_amdgcn_mfma_f32_16x16x32_bf16(av, bv, acc[nt], 0, 0, 0);
            }
        }

        const int rbase = row0 + 16 * w + lq * 4;
        const int cbase = ch * CH + lm;
#pragma unroll
        for (int nt = 0; nt < NT; nt++) {
#pragma unroll
            for (int r = 0; r < 4; r++) {
                int gr = rbase + r;
                if (gr < NN) {
                    float v = acc[nt][r];
                    if (relu) v = fmaxf(v, 0.0f);
                    C[(size_t)gr * Ntot + cbase + nt * 16] = f2bf(v);
                }
            }
        }
    }
}

// ======================= attention: shuffle-only, 4 independent waves/block =======================
// qkv layout: [N][3*OD] bf16 rows: [q | k | v]. Wave wv -> node blockIdx.x*4+wv.
// NO LDS, NO __syncthreads: all cross-lane traffic via __shfl (wave = sync domain).
// Phase 1: lanes = (16 edge-slots e x 4 heads h1); scores kept in regs p[t].
// Phase 2: lanes = (4 edge-subslots g x 16 dim-lanes dl); alpha/sn via shfl from
//          phase-1 layout (source lane = 4*(j&15)+h).
template<int DH>
__global__ __launch_bounds__(256) void attn_shfl_k(const uint16_t* __restrict__ qkv,
                                                   const int* __restrict__ rowptr,
                                                   const int* __restrict__ esrc,
                                                   uint16_t* __restrict__ agg,
                                                   float scale)
{
    constexpr int OD  = NH * DH;     // 128 / 64
    constexpr int STR = 3 * OD;
    constexpr int QU  = DH / 8;      // uint4 loads per head slice (4 / 2)
    constexpr int CAP = 64;          // edges per chunk (1 esrc load per lane)
    constexpr int NP  = CAP / 16;    // phase-1 passes (4)
    constexpr int FV  = OD / 16;     // dims per lane in phase 2 (8 / 4)

    const int wv   = threadIdx.x >> 6;
    const int lane = threadIdx.x & 63;
    const int n    = blockIdx.x * 4 + wv;      // NN % 4 == 0
    const int h1   = lane & 3;
    const int e    = lane >> 2;
    const int g    = lane >> 4;
    const int dl   = lane & 15;
    const int h2   = dl >> 2;                  // head owning dims [dl*FV, dl*FV+FV)

    // packed-bf16 q fragment for phase-1 head (keeps VGPRs <= 64 for 8 waves/SIMD)
    uint32_t qp[4 * QU];
    {
        const uint4* q4 = (const uint4*)(qkv + (size_t)n * STR + h1 * DH);
#pragma unroll
        for (int i = 0; i < QU; i++) {
            uint4 u = q4[i];
            qp[4 * i + 0] = u.x; qp[4 * i + 1] = u.y;
            qp[4 * i + 2] = u.z; qp[4 * i + 3] = u.w;
        }
    }

    const int j0 = rowptr[n], j1 = rowptr[n + 1];

    float m = -INFINITY, l = 0.0f;
    float acc[FV];
#pragma unroll
    for (int i = 0; i < FV; i++) acc[i] = 0.0f;

    const int voff = 2 * OD + dl * FV;

    for (int c0 = j0; c0 < j1; c0 += CAP) {
        const int cn = min(j1 - c0, CAP);
        const int sn_reg = (lane < cn) ? esrc[c0 + lane] : 0;

        // ---- phase 1: scores in regs ----
        float p[NP];
        float lm = -INFINITY;
#pragma unroll
        for (int t = 0; t < NP; t++) {
            const int j = e + 16 * t;
            float s = -INFINITY;
            if (j < cn) {
                const int sn = __shfl(sn_reg, j, 64);
                const uint4* kp = (const uint4*)(qkv + (size_t)sn * STR + OD + h1 * DH);
                s = 0.0f;
#pragma unroll
                for (int i = 0; i < QU; i++) {
                    uint4 u = kp[i];
                    s = fmaf(bf2f(qp[4 * i + 0] & 0xffffu), bf2f(u.x & 0xffffu), s);
                    s = fmaf(bf2f(qp[4 * i + 0] >> 16),     bf2f(u.x >> 16),     s);
                    s = fmaf(bf2f(qp[4 * i + 1] & 0xffffu), bf2f(u.y & 0xffffu), s);
                    s = fmaf(bf2f(qp[4 * i + 1] >> 16),     bf2f(u.y >> 16),     s);
                    s = fmaf(bf2f(qp[4 * i + 2] & 0xffffu), bf2f(u.z & 0xffffu), s);
                    s = fmaf(bf2f(qp[4 * i + 2] >> 16),     bf2f(u.z >> 16),     s);
                    s = fmaf(bf2f(qp[4 * i + 3] & 0xffffu), bf2f(u.w & 0xffffu), s);
                    s = fmaf(bf2f(qp[4 * i + 3] >> 16),     bf2f(u.w >> 16),     s);
                }
                s *= scale;
            }
            p[t] = s;
            lm = fmaxf(lm, s);
        }
#pragma unroll
        for (int msk = 4; msk <= 32; msk <<= 1) lm = fmaxf(lm, __shfl_xor(lm, msk, 64));
        const float mn = fmaxf(m, lm);
        const float corr = expf(m - mn);   // first chunk: exp(-inf) = 0 (acc already 0)
        m = mn;

        float ls = 0.0f;
#pragma unroll
        for (int t = 0; t < NP; t++) {
            const int j = e + 16 * t;
            float pe = (j < cn) ? expf(p[t] - mn) : 0.0f;
            p[t] = pe;
            ls += pe;
        }
#pragma unroll
        for (int msk = 4; msk <= 32; msk <<= 1) ls += __shfl_xor(ls, msk, 64);
        l = l * corr + ls;

        // ---- phase 2: 4 edges x 16 dim-lanes per pass ----
        const float c2 = __shfl(corr, h2, 64);   // lane h2 has h1 == h2
#pragma unroll
        for (int i = 0; i < FV; i++) acc[i] *= c2;

#pragma unroll
        for (int t = 0; t < NP; t++) {
            const int jend = min(cn, 16 * t + 16);
            for (int jb = 16 * t; jb < jend; jb += 4) {
                const int j = jb + g;                       // may be >= cn (alpha=0 then)
                const float alpha = __shfl(p[t], ((jb & 15) + g) * 4 + h2, 64);
                const int sn = __shfl(sn_reg, j, 64);       // lane >= cn holds 0 (safe addr)
                if constexpr (FV == 8) {
                    uint4 u = *(const uint4*)(qkv + (size_t)sn * STR + voff);
                    float vf[8];
                    unpk8(u, vf);
#pragma unroll
                    for (int i = 0; i < 8; i++) acc[i] = fmaf(alpha, vf[i], acc[i]);
                } else {
                    uint2 u = *(const uint2*)(qkv + (size_t)sn * STR + voff);
                    acc[0] = fmaf(alpha, bf2f(u.x & 0xffffu), acc[0]);
                    acc[1] = fmaf(alpha, bf2f(u.x >> 16),     acc[1]);
                    acc[2] = fmaf(alpha, bf2f(u.y & 0xffffu), acc[2]);
                    acc[3] = fmaf(alpha, bf2f(u.y >> 16),     acc[3]);
                }
            }
        }
    }

    // ---- epilogue: reduce over g, normalize, write ----
    const float lh = __shfl(l, h2, 64);
    const float inv = (lh > 0.0f) ? 1.0f / lh : 0.0f;
#pragma unroll
    for (int i = 0; i < FV; i++) {
        acc[i] += __shfl_xor(acc[i], 16, 64);
        acc[i] += __shfl_xor(acc[i], 32, 64);
    }
    if (g == 0) {
        uint16_t* op = agg + (size_t)n * OD + dl * FV;
        uint32_t wword[FV / 2];
#pragma unroll
        for (int i = 0; i < FV / 2; i++)
            wword[i] = (uint32_t)f2bf(acc[2 * i] * inv) | ((uint32_t)f2bf(acc[2 * i + 1] * inv) << 16);
        if constexpr (FV == 8) {
            *(uint4*)op = make_uint4(wword[0], wword[1], wword[2], wword[3]);
        } else {
            *(uint2*)op = make_uint2(wword[0], wword[1]);
        }
    }
}

// ======================= norms / dropout / reparam =======================
__global__ __launch_bounds__(256) void norm_relu_drop_k(const uint16_t* __restrict__ in,
                                                        uint16_t* __restrict__ out,
                                                        uint32_t k0, uint32_t k1)
{
    int row = blockIdx.x * 4 + (threadIdx.x >> 6);
    int lane = threadIdx.x & 63;
    if (row >= NN) return;
    const uint16_t* r = in + (size_t)row * 128;
    float a = bf2f(r[lane]), b = bf2f(r[lane + 64]);
    float ss = fmaf(a, a, b * b);
#pragma unroll
    for (int m = 32; m > 0; m >>= 1) ss += __shfl_xor(ss, m, 64);
    float d = fmaxf(sqrtf(ss), 1e-12f);
    float ya = fmaxf(a / d, 0.0f);
    float yb = fmaxf(b / d, 0.0f);
    uint32_t ia = (uint32_t)row * 128u + (uint32_t)lane;
    float ua = jax_u01(jax_bits32(k0, k1, ia));
    float ub = jax_u01(jax_bits32(k0, k1, ia + 64u));
    uint16_t* o = out + (size_t)row * 128;
    o[lane]      = f2bf((ua < 0.5f) ? ya * 2.0f : 0.0f);
    o[lane + 64] = f2bf((ub < 0.5f) ? yb * 2.0f : 0.0f);
}

__global__ __launch_bounds__(256) void norm64_k(const uint16_t* __restrict__ in,
                                                float* __restrict__ out)
{
    int row = blockIdx.x * 4 + (threadIdx.x >> 6);
    int lane = threadIdx.x & 63;
    if (row >= NN) return;
    float a = bf2f(in[(size_t)row * 64 + lane]);
    float ss = a * a;
#pragma unroll
    for (int m = 32; m > 0; m >>= 1) ss += __shfl_xor(ss, m, 64);
    float d = fmaxf(sqrtf(ss), 1e-12f);
    out[(size_t)row * 64 + lane] = a / d;
}

__global__ __launch_bounds__(256) void final_z_k(const float* __restrict__ mu,
                                                 const float* __restrict__ lv,
                                                 float* __restrict__ out,
                                                 uint32_t k0, uint32_t k1)
{
    int i = blockIdx.x * blockDim.x + threadIdx.x;
    if (i >= NN * 64) return;
    const float LO = -0.99999994f; // nextafter(-1, 0) in f32
    float u01 = jax_u01(jax_bits32(k0, k1, (uint32_t)i));
    float u = fmaxf(LO, fmaf(u01, 2.0f, LO));
    float eps = 1.41421354f * erfinv_f(u);
    float stdv = expf(lv[i]) + 1e-12f;
    out[i] = fmaf(eps, stdv, mu[i]);
}

// ======================= host side =======================
struct Bufs {
    uint16_t* Wt;
    uint16_t* feat_bf;
    uint16_t* qkv;
    uint16_t* agg;
    uint16_t* h1;
    uint16_t* h2;
    uint16_t* x;
    float* mu;
    float* lv;
    int* rowptr;
    int* cursor;
    int* bsums;
    int* esrc;
};

static void gemm_launch(int K, const uint16_t* A, const uint16_t* Wt, uint16_t* C,
                        int Ntot, int relu, hipStream_t s)
{
    int grid = (NN + 63) / 64;
    switch (K) {
    case 256: {
        size_t lds = (size_t)(64 + 32) * (256 + 8) * 2;
        gemm_mfma_k<256, 32><<<grid, 256, lds, s>>>(A, Wt, C, Ntot, relu);
        break;
    }
    case 128: {
        size_t lds = (size_t)(64 + 64) * (128 + 8) * 2;
        gemm_mfma_k<128, 64><<<grid, 256, lds, s>>>(A, Wt, C, Ntot, relu);
        break;
    }
    default: {
        size_t lds = (size_t)(64 + 64) * (64 + 8) * 2;
        gemm_mfma_k<64, 64><<<grid, 256, lds, s>>>(A, Wt, C, Ntot, relu);
        break;
    }
    }
}

static void run_gt_layer(const uint16_t* h_in, int K, int od,
                         const uint16_t* wqkv_t, const uint16_t* wo_t, bool relu,
                         uint16_t* h_out, const Bufs& B, hipStream_t stream)
{
    const int dh = od / NH;
    const float scale = 1.0f / sqrtf((float)dh);

    gemm_launch(K, h_in, wqkv_t, B.qkv, 3 * od, 0, stream);

    if (dh == 32)
        attn_shfl_k<32><<<NN / 4, 256, 0, stream>>>(B.qkv, B.rowptr, B.esrc, B.agg, scale);
    else
        attn_shfl_k<16><<<NN / 4, 256, 0, stream>>>(B.qkv, B.rowptr, B.esrc, B.agg, scale);

    gemm_launch(od, B.agg, wo_t, h_out, od, relu ? 1 : 0, stream);
}

extern "C" void kernel_launch(void* const* d_in, const int* in_sizes, int n_in,
                              void* d_out, int out_size, void* d_ws, size_t ws_size,
                              hipStream_t stream)
{
    const float* feat    = (const float*)d_in[0];
    const int*   src     = (const int*)d_in[1];
    const int*   dst     = (const int*)d_in[2];
    const float* wqkv1_0 = (const float*)d_in[3];
    const float* wqkv1_r = (const float*)d_in[4];
    const float* wo1     = (const float*)d_in[5];
    const float* wqkv2_0 = (const float*)d_in[6];
    const float* wqkv2_r = (const float*)d_in[7];
    const float* wo2     = (const float*)d_in[8];
    const float* wqkv3_0 = (const float*)d_in[9];
    const float* wqkv3_r = (const float*)d_in[10];
    const float* wo3     = (const float*)d_in[11];
    float* out = (float*)d_out;

    char* wp = (char*)d_ws;
    auto alloc = [&](size_t bytes) { char* p = wp; wp += (bytes + 255) & ~(size_t)255; return p; };

    WSegs segs;
    int offs[18];
    int acc_off = 0;
    auto seg = [&](int i, const float* p, int Bc, int Kc, int Cc) {
        segs.s[i].src = p; segs.s[i].B = Bc; segs.s[i].K = Kc; segs.s[i].C = Cc;
        segs.s[i].off = acc_off; offs[i] = acc_off; acc_off += Bc * Kc * Cc;
    };
    seg(0,  wqkv1_0,                 3, 256, 128);
    seg(1,  wqkv1_r,                 3, 128, 128);
    seg(2,  wqkv1_r + 3 * 128 * 128, 3, 128, 128);
    seg(3,  wo1,                     1, 128, 128);
    seg(4,  wo1 + 128 * 128,         1, 128, 128);
    seg(5,  wo1 + 2 * 128 * 128,     1, 128, 128);
    seg(6,  wqkv2_0,                 3, 128, 64);
    seg(7,  wqkv2_r,                 3, 64, 64);
    seg(8,  wqkv2_r + 3 * 64 * 64,   3, 64, 64);
    seg(9,  wo2,                     1, 64, 64);
    seg(10, wo2 + 64 * 64,           1, 64, 64);
    seg(11, wo2 + 2 * 64 * 64,       1, 64, 64);
    seg(12, wqkv3_0,                 3, 128, 64);
    seg(13, wqkv3_r,                 3, 64, 64);
    seg(14, wqkv3_r + 3 * 64 * 64,   3, 64, 64);
    seg(15, wo3,                     1, 64, 64);
    seg(16, wo3 + 64 * 64,           1, 64, 64);
    seg(17, wo3 + 2 * 64 * 64,       1, 64, 64);

    Bufs B;
    B.Wt      = (uint16_t*)alloc((size_t)acc_off * 2);
    B.feat_bf = (uint16_t*)alloc((size_t)NN * 256 * 2);
    B.qkv     = (uint16_t*)alloc((size_t)NN * 384 * 2);
    B.agg     = (uint16_t*)alloc((size_t)NN * 128 * 2);
    B.h1      = (uint16_t*)alloc((size_t)NN * 128 * 2);
    B.h2      = (uint16_t*)alloc((size_t)NN * 128 * 2);
    B.x       = (uint16_t*)alloc((size_t)NN * 128 * 2);
    B.mu      = (float*)alloc((size_t)NN * 64 * 4);
    B.lv      = (float*)alloc((size_t)NN * 64 * 4);
    B.rowptr  = (int*)alloc((size_t)(NN + 1) * 4);
    B.cursor  = (int*)alloc((size_t)NN * 4);
    B.bsums   = (int*)alloc((size_t)SCAN_NBLK * 4);
    B.esrc    = (int*)alloc((size_t)NE * 4);

    wconv_k<<<dim3(384, 18), 256, 0, stream>>>(segs, B.Wt);
    f2bf_vec_k<<<(NN * 256 / 4 + 255) / 256, 256, 0, stream>>>(feat, B.feat_bf, NN * 256);

    fill_u32_k<<<(NN + 255) / 256, 256, 0, stream>>>((uint32_t*)B.cursor, 0u, NN);
    hist_k<<<(NE + 255) / 256, 256, 0, stream>>>(dst, B.cursor);
    scan1_k<<<SCAN_NBLK, 256, 0, stream>>>(B.cursor, B.rowptr, B.bsums);
    scan2_k<<<1, 64, 0, stream>>>(B.bsums);
    scan3_k<<<(NN + 255) / 256, 256, 0, stream>>>(B.rowptr, B.bsums, B.cursor);
    csr_scatter_k<<<(NE + 255) / 256, 256, 0, stream>>>(src, dst, B.cursor, B.esrc);

    uint32_t kd0, kd1, ke0, ke1;
    tf2x32(0u, 42u, 0u, 0u, kd0, kd1);
    tf2x32(0u, 42u, 0u, 1u, ke0, ke1);

    run_gt_layer(B.feat_bf, 256, 128, B.Wt + offs[0], B.Wt + offs[3], true,  B.h1, B, stream);
    run_gt_layer(B.h1,      128, 128, B.Wt + offs[1], B.Wt + offs[4], true,  B.h2, B, stream);
    run_gt_layer(B.h2,      128, 128, B.Wt + offs[2], B.Wt + offs[5], false, B.h1, B, stream);

    norm_relu_drop_k<<<NN / 4, 256, 0, stream>>>(B.h1, B.x, kd0, kd1);

    run_gt_layer(B.x,  128, 64, B.Wt + offs[6], B.Wt + offs[9],  true,  B.h1, B, stream);
    run_gt_layer(B.h1, 64,  64, B.Wt + offs[7], B.Wt + offs[10], true,  B.h2, B, stream);
    run_gt_layer(B.h2, 64,  64, B.Wt + offs[8], B.Wt + offs[11], false, B.h1, B, stream);
    norm64_k<<<NN / 4, 256, 0, stream>>>(B.h1, B.mu);

    run_gt_layer(B.x,  128, 64, B.Wt + offs[12], B.Wt + offs[15], true,  B.h1, B, stream);
    run_gt_layer(B.h1, 64,  64, B.Wt + offs[13], B.Wt + offs[16], true,  B.h2, B, stream);
    run_gt_layer(B.h2, 64,  64, B.Wt + offs[14], B.Wt + offs[17], false, B.h1, B, stream);
    norm64_k<<<NN / 4, 256, 0, stream>>>(B.h1, B.lv);

    final_z_k<<<(NN * 64 + 255) / 256, 256, 0, stream>>>(B.mu, B.lv, out, ke0, ke1);
}